// Round 3
// baseline (98.740 us; speedup 1.0000x reference)
//
#include <hip/hip_runtime.h>

// Problem constants (match reference)
#define HH 256
#define WW 512
#define NB 128
#define N_STUFF 11
#define N_SEG 19

typedef float f4 __attribute__((ext_vector_type(4)));

constexpr int W4       = WW / 4;                  // 128 float4 groups per row
constexpr int PLANE_N4 = HH * W4;                 // 32768 groups per plane
constexpr int STUFF_N4 = N_STUFF * PLANE_N4;      // 360448 groups

// Strategy: hipMemsetAsync zeroes the 67 MB instance region at the driver
// fill's proven 6.2 TB/s; the kernel only writes the stuff copy (5.8 MB r+w)
// and the interior of each box (~2.4% of each plane). Kernel traffic ~14 MB.
constexpr int GPT          = 4;                   // float4 groups per thread (copy)
constexpr int GPB          = 256 * GPT;           // 1024 groups per block
constexpr int STUFF_BLOCKS = STUFF_N4 / GPB;      // 352 (exact)
constexpr int BPB          = 4;                   // blocks per box (row-split)
constexpr int TOTAL_BLOCKS = STUFF_BLOCKS + NB * BPB;  // 864

__global__ __launch_bounds__(256)
void SegTerm_kernel(const int* __restrict__ cls,
                    const float* __restrict__ seg,
                    const float* __restrict__ boxes,
                    float* __restrict__ out)
{
    const int blk = blockIdx.x;
    const int t   = threadIdx.x;

    if (blk < STUFF_BLOCKS) {
        // Output 0: straight copy (plain stores — the fill proves they stream
        // at 6.2 TB/s; NT hints regressed in round 2).
        const f4* __restrict__ s4 = (const f4*)seg;
        f4* __restrict__       o4 = (f4*)out;
        const int base = blk * GPB + t;
        #pragma unroll
        for (int k = 0; k < GPT; ++k)
            o4[base + k * 256] = s4[base + k * 256];
        return;
    }

    // Output 1: write ONLY the box interior (rest is already memset to 0).
    const int b2   = blk - STUFF_BLOCKS;
    const int box  = b2 >> 2;                     // BPB = 4
    const int part = b2 & 3;

    const int c = cls[box];                       // block-uniform
    if (c == 0) return;

    // b = boxes[:,1:] * 0.25 (exact in fp32); jnp.round = RNE -> rintf
    const float bx0 = boxes[box * 5 + 1] * 0.25f;
    const float by0 = boxes[box * 5 + 2] * 0.25f;
    const float bx1 = boxes[box * 5 + 3] * 0.25f;
    const float by1 = boxes[box * 5 + 4] * 0.25f;
    const int x0 = (int)floorf(bx0);
    const int y0 = (int)floorf(by0);
    const int x1 = (int)(rintf(bx1) + 1.0f);      // can reach 513
    const int y1 = (int)(rintf(by1) + 1.0f);      // can reach 257

    const int ylo0 = max(y0, 0), yhi = min(y1, HH);
    const int xlo  = max(x0, 0), xhi = min(x1, WW);
    if (ylo0 >= yhi || xlo >= xhi) return;

    // Split the box's rows among the 4 parts.
    const int rows = yhi - ylo0;
    const int rpp  = (rows + BPB - 1) >> 2;
    const int ylo  = ylo0 + part * rpp;
    const int yh2  = min(ylo + rpp, yhi);
    if (ylo >= yh2) return;

    const int mapped = min(c + 10, N_SEG - 1);
    const float* __restrict__ src = seg + (size_t)mapped * HH * WW;  // L2-resident
    float* __restrict__       dst = out + (size_t)N_STUFF * HH * WW
                                        + (size_t)box * HH * WW;

    for (int y = ylo; y < yh2; ++y) {
        const float* __restrict__ sr = src + y * WW;
        float* __restrict__       dr = dst + y * WW;
        // Lane-consecutive columns -> coalesced 4B accesses; total bytes tiny.
        for (int x = xlo + t; x < xhi; x += 256)
            dr[x] = sr[x];
    }
}

extern "C" void kernel_launch(void* const* d_in, const int* in_sizes, int n_in,
                              void* d_out, int out_size, void* d_ws, size_t ws_size,
                              hipStream_t stream) {
    const int*   cls   = (const int*)d_in[0];
    const float* seg   = (const float*)d_in[1];
    const float* boxes = (const float*)d_in[2];
    float*       out   = (float*)d_out;

    // Zero the instance region (67 MB) via the driver's 6.2 TB/s fill path.
    // hipMemsetAsync on-stream is graph-capturable (the harness's own reset
    // uses it). 4 KB-aligned offset, size multiple of 16 B.
    const size_t stuff_floats = (size_t)N_STUFF * HH * WW;
    const size_t inst_bytes   = (size_t)NB * HH * WW * sizeof(float);
    hipMemsetAsync(out + stuff_floats, 0, inst_bytes, stream);

    SegTerm_kernel<<<TOTAL_BLOCKS, 256, 0, stream>>>(cls, seg, boxes, out);
}

// Round 4
// 88.424 us; speedup vs baseline: 1.1167x; 1.1167x over previous
//
#include <hip/hip_runtime.h>

// Problem constants (match reference)
#define HH 256
#define WW 512
#define NB 128
#define N_STUFF 11
#define N_SEG 19

constexpr int W4       = WW / 4;                  // 128 float4 groups per row
constexpr int STUFF_N4 = N_STUFF * HH * W4;       // 360448 float4 groups
constexpr int BOX_N4   = HH * W4;                 // 32768 groups per box plane

// One dispatch. 256-thread blocks, 4 float4 groups per thread (stride 256):
//   blocks [0, STUFF_BLOCKS)  : copy first 11 channels (output 0)
//   blocks [STUFF_BLOCKS, +NB*32) : instance planes, 8 rows per block (output 1)
// 4448 blocks = 17.4 blocks/CU: oversubscribed grid gives dynamic load
// balancing; measured best config (89.2/92.0 us). Fatter-wave (R2) and
// memset+sparse-write (R3) variants both regressed — dur_us is dominated by
// ~83 us of harness reset; kernel-side is ~9 us, at the L2-absorbed write floor.
constexpr int STUFF_BLOCKS = STUFF_N4 / 1024;     // 352 (exact)
constexpr int INST_BLOCKS  = NB * BOX_N4 / 1024;  // 4096
constexpr int TOTAL_BLOCKS = STUFF_BLOCKS + INST_BLOCKS;  // 4448

__global__ __launch_bounds__(256)
void SegTerm_kernel(const int* __restrict__ cls,
                    const float4* __restrict__ seg4,
                    const float* __restrict__ boxes,
                    float4* __restrict__ out4)
{
    const int blk = blockIdx.x;
    const int t   = threadIdx.x;

    if (blk < STUFF_BLOCKS) {
        // Output 0: straight copy, 4 independent float4 per thread.
        const int base = blk * 1024 + t;
        #pragma unroll
        for (int k = 0; k < 4; ++k)
            out4[base + k * 256] = seg4[base + k * 256];
        return;
    }

    // Output 1: one block covers 8 rows of one box's plane.
    const int b2          = blk - STUFF_BLOCKS;
    const int box         = b2 >> 5;              // 32 blocks per box
    const int base_in_box = (b2 & 31) * 1024;     // group index within plane
    float4* __restrict__ dst = out4 + STUFF_N4 + (size_t)box * BOX_N4;

    const float4 zero = make_float4(0.f, 0.f, 0.f, 0.f);
    const int c = cls[box];                       // block-uniform (scalar)

    if (c == 0) {
        #pragma unroll
        for (int k = 0; k < 4; ++k)
            dst[base_in_box + k * 256 + t] = zero;
        return;
    }

    // b = boxes[:,1:] * 0.25 (exact in fp32); jnp.round = RNE -> rintf
    const float bx0 = boxes[box * 5 + 1] * 0.25f;
    const float by0 = boxes[box * 5 + 2] * 0.25f;
    const float bx1 = boxes[box * 5 + 3] * 0.25f;
    const float by1 = boxes[box * 5 + 4] * 0.25f;
    const int x0 = (int)floorf(bx0);
    const int y0 = (int)floorf(by0);
    const int x1 = (int)(rintf(bx1) + 1.0f);
    const int y1 = (int)(rintf(by1) + 1.0f);

    const int mapped = min(c + 10, N_SEG - 1);
    const float4* __restrict__ src = seg4 + (size_t)mapped * BOX_N4;

    #pragma unroll
    for (int k = 0; k < 4; ++k) {
        const int gi = base_in_box + k * 256 + t;
        const int y  = gi >> 7;                   // row within plane
        const int xg = gi & (W4 - 1);
        const int x  = xg << 2;

        float4 v = zero;
        if (y >= y0 && y < y1) {
            if (x >= x0 && x + 3 < x1) {
                v = src[(y << 7) + xg];           // fully-interior: aligned 16B
            } else if (x + 3 >= x0 && x < x1) {
                const float* s = (const float*)(src + (y << 7)) + x;
                const float e0 = (x     >= x0 && x     < x1) ? s[0] : 0.f;
                const float e1 = (x + 1 >= x0 && x + 1 < x1) ? s[1] : 0.f;
                const float e2 = (x + 2 >= x0 && x + 2 < x1) ? s[2] : 0.f;
                const float e3 = (x + 3 >= x0 && x + 3 < x1) ? s[3] : 0.f;
                v = make_float4(e0, e1, e2, e3);
            }
        }
        dst[gi] = v;
    }
}

extern "C" void kernel_launch(void* const* d_in, const int* in_sizes, int n_in,
                              void* d_out, int out_size, void* d_ws, size_t ws_size,
                              hipStream_t stream) {
    const int*    cls   = (const int*)d_in[0];
    const float4* seg4  = (const float4*)d_in[1];
    const float*  boxes = (const float*)d_in[2];
    float4*       out4  = (float4*)d_out;

    SegTerm_kernel<<<TOTAL_BLOCKS, 256, 0, stream>>>(cls, seg4, boxes, out4);
}